// Round 3
// baseline (321.617 us; speedup 1.0000x reference)
//
#include <hip/hip_runtime.h>

// LinearAttention fused pipeline for MI355X (gfx950) — round 3.
// Key change vs r2: NO strided global loads. x tiles staged natural-layout via
// async global_load_lds (coalesced 1KB/inst), transpose folded into MFMA
// B-fragment construction from LDS (b32 column reads).
// b=32, C=128, n=4096, H=4 heads, D=32 head-dim.
//
// ws: ctx_u[32][4][32][32] f32 | Z[32][128] f32 | stats[32][2] f32 | wb 4x16384 bf16

#define B_   32
#define C_   128
#define N_   4096
#define H_   4
#define D_   32
#define HID  128
#define NB   64
#define STV  72       // ek/v row stride (shorts)
#define STA  136      // qeq/attnT row stride (shorts)
#define SCT  40       // ctxT row stride (shorts)
#define SCALE 0.1767766952966369f
#define EPS  1e-5f

typedef __attribute__((ext_vector_type(8))) short short8;
typedef __attribute__((ext_vector_type(4))) short short4v;
typedef __attribute__((ext_vector_type(4))) float floatx4;

__device__ __forceinline__ short f2bf(float f) {   // RNE fp32 -> bf16
  unsigned u = __float_as_uint(f);
  u += 0x7FFFu + ((u >> 16) & 1u);
  return (short)(u >> 16);
}
__device__ __forceinline__ float bf2f(short h) {
  return __uint_as_float(((unsigned)(unsigned short)h) << 16);
}
__device__ __forceinline__ void gload_lds16(const float* g, void* l) {
  __builtin_amdgcn_global_load_lds(
      (const __attribute__((address_space(1))) unsigned int*)g,
      (__attribute__((address_space(3))) unsigned int*)l, 16, 0, 0);
}

// ---------------------------------------------------------------- K0: weights -> bf16
__global__ __launch_bounds__(256) void k_wcast(
    const float* __restrict__ Wq, const float* __restrict__ Wk,
    const float* __restrict__ Wv, const float* __restrict__ Wo,
    short* __restrict__ wb) {
  const int i = blockIdx.x * 256 + threadIdx.x;   // 0..16383, 4 elems each
  const float* srcs[4] = {Wq, Wk, Wv, Wo};
#pragma unroll
  for (int m = 0; m < 4; ++m) {
    floatx4 a = ((const floatx4*)srcs[m])[i];
    short4v s = { f2bf(a[0]), f2bf(a[1]), f2bf(a[2]), f2bf(a[3]) };
    ((short4v*)(wb + m * 16384))[i] = s;
  }
}

// ---------------------------------------------------------------- K1: k,v proj + ctx/Z
__global__ __launch_bounds__(256, 4) void k_kv_ctx(
    const float* __restrict__ x, const short* __restrict__ Wkb,
    const short* __restrict__ Wvb, float* __restrict__ ctx_u,
    float* __restrict__ Zsum) {
  __shared__ float smemf[9216];                    // 36864 B
  float* natx  = smemf;                            // [128][64] f32 (staging)
  short* vbuf  = (short*)smemf;                    // [128][STV] bf16 (after natx dead)
  short* ekbuf = (short*)smemf + 9216;             // [128][STV] bf16
  const int tid = threadIdx.x;
  const int w = tid >> 6, L = tid & 63, l15 = tid & 15, q4 = (tid & 63) >> 4;
  const int b = blockIdx.x >> 6;
  const int n0 = (blockIdx.x & 63) * NB;
  const float* xb = x + (size_t)b * C_ * N_ + n0;

  // async stage: wave w stages rows [32w, 32w+32), 8 insts x 1KB, coalesced
#pragma unroll
  for (int i = 0; i < 8; ++i) {
    const int c = w * 32 + i * 4 + (L >> 4);
    gload_lds16(xb + (size_t)c * N_ + (L & 15) * 4,
                (char*)natx + ((w * 32 + i * 4) * 64 + L * 4) * 4);
  }
  __syncthreads();   // b1: x tile staged

  const floatx4 z4 = {0.f, 0.f, 0.f, 0.f};
  floatx4 acck[2][4], accv[2][4];
#pragma unroll
  for (int mt = 0; mt < 2; ++mt)
#pragma unroll
    for (int nt = 0; nt < 4; ++nt) { acck[mt][nt] = z4; accv[mt][nt] = z4; }

  // k and v GEMMs interleaved; B-frags built from natural-layout LDS
#pragma unroll
  for (int ks = 0; ks < 4; ++ks) {
    short8 ak[2], av[2];
#pragma unroll
    for (int mt = 0; mt < 2; ++mt) {
      ak[mt] = *(const short8*)&Wkb[(w * 32 + mt * 16 + l15) * C_ + ks * 32 + q4 * 8];
      av[mt] = *(const short8*)&Wvb[(w * 32 + mt * 16 + l15) * C_ + ks * 32 + q4 * 8];
    }
    short8 Bf[4];
#pragma unroll
    for (int nt = 0; nt < 4; ++nt) {
      short8 s;
#pragma unroll
      for (int j = 0; j < 8; ++j)
        s[j] = f2bf(natx[(ks * 32 + q4 * 8 + j) * 64 + nt * 16 + l15]);
      Bf[nt] = s;
    }
#pragma unroll
    for (int mt = 0; mt < 2; ++mt)
#pragma unroll
      for (int nt = 0; nt < 4; ++nt) {
        acck[mt][nt] = __builtin_amdgcn_mfma_f32_16x16x32_bf16(ak[mt], Bf[nt], acck[mt][nt], 0, 0, 0);
        accv[mt][nt] = __builtin_amdgcn_mfma_f32_16x16x32_bf16(av[mt], Bf[nt], accv[mt][nt], 0, 0, 0);
      }
  }

  // exp(k)
#pragma unroll
  for (int mt = 0; mt < 2; ++mt)
#pragma unroll
    for (int nt = 0; nt < 4; ++nt)
#pragma unroll
      for (int r = 0; r < 4; ++r)
        acck[mt][nt][r] = __expf(acck[mt][nt][r]);

  // Z row-sums via shuffle (rows d = w*32+mt*16+q4*4+r; sum over nt then l15)
#pragma unroll
  for (int mt = 0; mt < 2; ++mt)
#pragma unroll
    for (int r = 0; r < 4; ++r) {
      float s = acck[mt][0][r] + acck[mt][1][r] + acck[mt][2][r] + acck[mt][3][r];
      s += __shfl_xor(s, 1); s += __shfl_xor(s, 2);
      s += __shfl_xor(s, 4); s += __shfl_xor(s, 8);
      if (l15 == 0) atomicAdd(&Zsum[b * HID + w * 32 + mt * 16 + q4 * 4 + r], s);
    }

  __syncthreads();   // b2: all waves done reading natx — region reusable

  // pack ek, v into LDS (wave-local rows)
#pragma unroll
  for (int mt = 0; mt < 2; ++mt)
#pragma unroll
    for (int nt = 0; nt < 4; ++nt)
#pragma unroll
      for (int r = 0; r < 4; ++r) {
        ekbuf[(w * 32 + mt * 16 + q4 * 4 + r) * STV + nt * 16 + l15] = f2bf(acck[mt][nt][r]);
        vbuf [(w * 32 + mt * 16 + q4 * 4 + r) * STV + nt * 16 + l15] = f2bf(accv[mt][nt][r]);
      }

  // ctx partial via MFMA (wave-local rows, in-wave DS ordering — no barrier)
  {
    floatx4 ca[2][2] = {{z4, z4}, {z4, z4}};
#pragma unroll
    for (int ks = 0; ks < 2; ++ks) {
      short8 ae[2], be[2];
#pragma unroll
      for (int mt = 0; mt < 2; ++mt)
        ae[mt] = *(const short8*)&ekbuf[(w * 32 + mt * 16 + l15) * STV + ks * 32 + q4 * 8];
#pragma unroll
      for (int nt = 0; nt < 2; ++nt)
        be[nt] = *(const short8*)&vbuf[(w * 32 + nt * 16 + l15) * STV + ks * 32 + q4 * 8];
#pragma unroll
      for (int mt = 0; mt < 2; ++mt)
#pragma unroll
        for (int nt = 0; nt < 2; ++nt)
          ca[mt][nt] = __builtin_amdgcn_mfma_f32_16x16x32_bf16(ae[mt], be[nt], ca[mt][nt], 0, 0, 0);
    }
    float* cb = &ctx_u[((size_t)b * H_ + w) * (D_ * D_)];
#pragma unroll
    for (int mt = 0; mt < 2; ++mt)
#pragma unroll
      for (int nt = 0; nt < 2; ++nt)
#pragma unroll
        for (int r = 0; r < 4; ++r)
          atomicAdd(&cb[(mt * 16 + q4 * 4 + r) * D_ + nt * 16 + l15], ca[mt][nt][r]);
  }
}

// ---------------------------------------------------------------- K2: q proj + attn + Wo + stats
__global__ __launch_bounds__(256, 4) void k_q_attn_o(
    const float* __restrict__ x, const short* __restrict__ Wqb,
    const short* __restrict__ Wob, const float* __restrict__ bo,
    const float* __restrict__ ctx_u, const float* __restrict__ Zsum,
    float* __restrict__ outp, float* __restrict__ stats) {
  __shared__ float smemf[8192];                    // 32768 B
  float* natx = smemf;                             // [128][64] f32 (staging)
  short* qat  = (short*)smemf;                     // [64][STA]: eq^T then attn^T
  short* ctxT = (short*)smemf + 8704;              // [128][SCT] bf16 @17408B
  const int tid = threadIdx.x;
  const int w = tid >> 6, L = tid & 63, l15 = tid & 15, q4 = (tid & 63) >> 4;
  const int b = blockIdx.x >> 6;
  const int n0 = (blockIdx.x & 63) * NB;
  const float* xb = x + (size_t)b * C_ * N_ + n0;

  // async stage x tile (same as K1)
#pragma unroll
  for (int i = 0; i < 8; ++i) {
    const int c = w * 32 + i * 4 + (L >> 4);
    gload_lds16(xb + (size_t)c * N_ + (L & 15) * 4,
                (char*)natx + ((w * 32 + i * 4) * 64 + L * 4) * 4);
  }

  // preload q A-frags while staging is in flight
  short8 aq[2][4];
#pragma unroll
  for (int mt = 0; mt < 2; ++mt)
#pragma unroll
    for (int ks = 0; ks < 4; ++ks)
      aq[mt][ks] = *(const short8*)&Wqb[(w * 32 + mt * 16 + l15) * C_ + ks * 32 + q4 * 8];
  __syncthreads();   // b1

  const floatx4 z4 = {0.f, 0.f, 0.f, 0.f};
  floatx4 acc[2][4];
#pragma unroll
  for (int mt = 0; mt < 2; ++mt)
#pragma unroll
    for (int nt = 0; nt < 4; ++nt) acc[mt][nt] = z4;

  // q = Wq @ x
#pragma unroll
  for (int ks = 0; ks < 4; ++ks) {
    short8 Bf[4];
#pragma unroll
    for (int nt = 0; nt < 4; ++nt) {
      short8 s;
#pragma unroll
      for (int j = 0; j < 8; ++j)
        s[j] = f2bf(natx[(ks * 32 + q4 * 8 + j) * 64 + nt * 16 + l15]);
      Bf[nt] = s;
    }
#pragma unroll
    for (int mt = 0; mt < 2; ++mt)
#pragma unroll
      for (int nt = 0; nt < 4; ++nt)
        acc[mt][nt] = __builtin_amdgcn_mfma_f32_16x16x32_bf16(aq[mt][ks], Bf[nt], acc[mt][nt], 0, 0, 0);
  }
  __syncthreads();   // b2: natx dead

  // exp(q); per-column softmax denom via shuffle (sum over mt,r then q4)
#pragma unroll
  for (int mt = 0; mt < 2; ++mt)
#pragma unroll
    for (int nt = 0; nt < 4; ++nt)
#pragma unroll
      for (int r = 0; r < 4; ++r)
        acc[mt][nt][r] = __expf(acc[mt][nt][r]);
  float inv[4];
#pragma unroll
  for (int nt = 0; nt < 4; ++nt) {
    float s = 0.f;
#pragma unroll
    for (int mt = 0; mt < 2; ++mt)
#pragma unroll
      for (int r = 0; r < 4; ++r) s += acc[mt][nt][r];
    s += __shfl_xor(s, 16); s += __shfl_xor(s, 32);
    inv[nt] = SCALE * __builtin_amdgcn_rcpf(s);
  }

  // scaled eq^T into qat (wave-column-disjoint, in-wave ordering)
#pragma unroll
  for (int mt = 0; mt < 2; ++mt)
#pragma unroll
    for (int nt = 0; nt < 4; ++nt) {
      short4v pk = { f2bf(acc[mt][nt][0] * inv[nt]), f2bf(acc[mt][nt][1] * inv[nt]),
                     f2bf(acc[mt][nt][2] * inv[nt]), f2bf(acc[mt][nt][3] * inv[nt]) };
      *(short4v*)&qat[(nt * 16 + l15) * STA + w * 32 + mt * 16 + q4 * 4] = pk;
    }

  // ctxT[e + 32h][d] = ctx_u[h,d,e] / Z[h*32+d]  (overlays natx tail region)
#pragma unroll
  for (int i = 0; i < 16; ++i) {
    const int idx = tid + i * 256;               // h*1024 + d*32 + e
    float v = ctx_u[(size_t)b * (H_ * D_ * D_) + idx] *
              __builtin_amdgcn_rcpf(Zsum[b * HID + (idx >> 5)]);
    ctxT[((idx >> 10) * 32 + (idx & 31)) * SCT + ((idx >> 5) & 31)] = f2bf(v);
  }
  __syncthreads();   // b3: ctxT ready (qat is wave-local until Wo)

  // attn: out[e][n] = sum_d ctxT[e][d] * eq[d][n]  (8 MFMA, K=32)
  {
    floatx4 aacc[2][4];
#pragma unroll
    for (int mt = 0; mt < 2; ++mt)
#pragma unroll
      for (int nt = 0; nt < 4; ++nt) aacc[mt][nt] = z4;
    short8 ae[2];
#pragma unroll
    for (int mt = 0; mt < 2; ++mt)
      ae[mt] = *(const short8*)&ctxT[(w * 32 + mt * 16 + l15) * SCT + q4 * 8];
#pragma unroll
    for (int nt = 0; nt < 4; ++nt) {
      short8 bq = *(const short8*)&qat[(nt * 16 + l15) * STA + w * 32 + q4 * 8];
#pragma unroll
      for (int mt = 0; mt < 2; ++mt)
        aacc[mt][nt] = __builtin_amdgcn_mfma_f32_16x16x32_bf16(ae[mt], bq, aacc[mt][nt], 0, 0, 0);
    }
    // attn^T over eq^T (same wave-local columns)
#pragma unroll
    for (int nt = 0; nt < 4; ++nt)
#pragma unroll
      for (int mt = 0; mt < 2; ++mt) {
        short4v pk = { f2bf(aacc[mt][nt][0]), f2bf(aacc[mt][nt][1]),
                       f2bf(aacc[mt][nt][2]), f2bf(aacc[mt][nt][3]) };
        *(short4v*)&qat[(nt * 16 + l15) * STA + w * 32 + mt * 16 + q4 * 4] = pk;
      }
  }
  __syncthreads();   // b4: attn^T visible to all waves

  // out_pre = Wo @ attn + bo
#pragma unroll
  for (int mt = 0; mt < 2; ++mt)
#pragma unroll
    for (int nt = 0; nt < 4; ++nt) acc[mt][nt] = z4;
#pragma unroll
  for (int ks = 0; ks < 4; ++ks) {
    short8 ao[2];
#pragma unroll
    for (int mt = 0; mt < 2; ++mt)
      ao[mt] = *(const short8*)&Wob[(w * 32 + mt * 16 + l15) * HID + ks * 32 + q4 * 8];
    short8 bf8[4];
#pragma unroll
    for (int nt = 0; nt < 4; ++nt)
      bf8[nt] = *(const short8*)&qat[(nt * 16 + l15) * STA + ks * 32 + q4 * 8];
#pragma unroll
    for (int mt = 0; mt < 2; ++mt)
#pragma unroll
      for (int nt = 0; nt < 4; ++nt)
        acc[mt][nt] = __builtin_amdgcn_mfma_f32_16x16x32_bf16(ao[mt], bf8[nt], acc[mt][nt], 0, 0, 0);
  }

  // epilogue: +bo, store, per-batch stats
  float s1 = 0.f, s2 = 0.f;
#pragma unroll
  for (int mt = 0; mt < 2; ++mt) {
    const int rowbase = w * 32 + mt * 16 + q4 * 4;
    const floatx4 bo4 = *(const floatx4*)&bo[rowbase];
#pragma unroll
    for (int nt = 0; nt < 4; ++nt) {
      const int n = n0 + nt * 16 + l15;
#pragma unroll
      for (int r = 0; r < 4; ++r) {
        float vv = acc[mt][nt][r] + bo4[r];
        outp[(size_t)b * (C_ * N_) + (size_t)(rowbase + r) * N_ + n] = vv;
        s1 += vv; s2 += vv * vv;
      }
    }
  }
#pragma unroll
  for (int m = 1; m < 64; m <<= 1) {
    s1 += __shfl_xor(s1, m);
    s2 += __shfl_xor(s2, m);
  }
  if ((tid & 63) == 0) {
    atomicAdd(&stats[b * 2 + 0], s1);
    atomicAdd(&stats[b * 2 + 1], s2);
  }
}

// ---------------------------------------------------------------- K3: GroupNorm
__global__ __launch_bounds__(256) void k_gnorm(
    float* __restrict__ outp, const float* __restrict__ stats,
    const float* __restrict__ gnw, const float* __restrict__ gnb) {
  const int b = blockIdx.x >> 6;
  const int blk = blockIdx.x & 63;
  const float M = (float)(C_ * N_);
  const float mu = stats[b * 2 + 0] / M;
  const float var = stats[b * 2 + 1] / M - mu * mu;
  const float rs = rsqrtf(var + EPS);
  floatx4* p = (floatx4*)(outp + (size_t)b * (C_ * N_) + (size_t)blk * 8192);
  const int tid = threadIdx.x;
#pragma unroll
  for (int i = 0; i < 8; ++i) {
    const int idx = tid + i * 256;
    const int fl = blk * 8192 + idx * 4;
    const int c = fl >> 12;
    const float wgt = gnw[c] * rs;
    const float bia = gnb[c] - mu * wgt;
    floatx4 v = p[idx];
    v[0] = v[0] * wgt + bia;
    v[1] = v[1] * wgt + bia;
    v[2] = v[2] * wgt + bia;
    v[3] = v[3] * wgt + bia;
    p[idx] = v;
  }
}

// ---------------------------------------------------------------- launch
extern "C" void kernel_launch(void* const* d_in, const int* in_sizes, int n_in,
                              void* d_out, int out_size, void* d_ws, size_t ws_size,
                              hipStream_t stream) {
  (void)in_sizes; (void)n_in; (void)out_size; (void)ws_size;
  const float* x   = (const float*)d_in[0];
  const float* Wq  = (const float*)d_in[1];
  const float* Wk  = (const float*)d_in[2];
  const float* Wv  = (const float*)d_in[3];
  const float* Wo  = (const float*)d_in[4];
  const float* bo  = (const float*)d_in[5];
  const float* gnw = (const float*)d_in[6];
  const float* gnb = (const float*)d_in[7];
  float* outp  = (float*)d_out;
  float* ctx_u = (float*)d_ws;                       // 131072 f
  float* Zsum  = ctx_u + B_ * H_ * D_ * D_;          // 4096 f
  float* stats = Zsum + B_ * HID;                    // 64 f
  short* wb    = (short*)(stats + B_ * 2);           // 4 x 16384 bf16
  const size_t zbytes = (size_t)(B_ * H_ * D_ * D_ + B_ * HID + B_ * 2) * sizeof(float);
  hipMemsetAsync(d_ws, 0, zbytes, stream);
  hipLaunchKernelGGL(k_wcast,    dim3(64),      dim3(256), 0, stream, Wq, Wk, Wv, Wo, wb);
  hipLaunchKernelGGL(k_kv_ctx,   dim3(B_ * 64), dim3(256), 0, stream, x, wb + 16384, wb + 32768, ctx_u, Zsum);
  hipLaunchKernelGGL(k_q_attn_o, dim3(B_ * 64), dim3(256), 0, stream, x, wb, wb + 49152, bo, ctx_u, Zsum, outp, stats);
  hipLaunchKernelGGL(k_gnorm,    dim3(B_ * 64), dim3(256), 0, stream, outp, stats, gnw, gnb);
}

// Round 4
// 206.986 us; speedup vs baseline: 1.5538x; 1.5538x over previous
//
#include <hip/hip_runtime.h>

// LinearAttention fused pipeline for MI355X (gfx950) — round 4.
// Key change vs r3: 4 n-tiles per block (grid 2048->512). Amortizes page
// walks over the 128 strided rows, makes weights/ctx register/LDS-resident
// across tiles, overlaps tile t+1 staging with tile t wave-local compute,
// and cuts ctx/Z/stats atomics 4x by register accumulation across tiles.
// b=32, C=128, n=4096, H=4 heads, D=32 head-dim.
//
// ws: ctx_u[32][4][32][32] f32 | Z[32][128] f32 | stats[32][2] f32 | wb 4x16384 bf16

#define B_   32
#define C_   128
#define N_   4096
#define H_   4
#define D_   32
#define HID  128
#define NB   64
#define TPB  4        // n-tiles per block
#define NSTRIP 16     // strips per batch (NSTRIP*TPB*NB == N_)
#define STV  72       // ek/v row stride (shorts)
#define STA  136      // eqT/attnT row stride (shorts)
#define SCT  40       // ctxT row stride (shorts)
#define SCALE 0.1767766952966369f
#define EPS  1e-5f

typedef __attribute__((ext_vector_type(8))) short short8;
typedef __attribute__((ext_vector_type(4))) short short4v;
typedef __attribute__((ext_vector_type(4))) float floatx4;

__device__ __forceinline__ short f2bf(float f) {   // RNE fp32 -> bf16
  unsigned u = __float_as_uint(f);
  u += 0x7FFFu + ((u >> 16) & 1u);
  return (short)(u >> 16);
}
__device__ __forceinline__ float bf2f(short h) {
  return __uint_as_float(((unsigned)(unsigned short)h) << 16);
}
__device__ __forceinline__ void gload_lds16(const float* g, void* l) {
  __builtin_amdgcn_global_load_lds(
      (const __attribute__((address_space(1))) unsigned int*)g,
      (__attribute__((address_space(3))) unsigned int*)l, 16, 0, 0);
}

// ---------------------------------------------------------------- K0: weights -> bf16
__global__ __launch_bounds__(256) void k_wcast(
    const float* __restrict__ Wq, const float* __restrict__ Wk,
    const float* __restrict__ Wv, const float* __restrict__ Wo,
    short* __restrict__ wb) {
  const int i = blockIdx.x * 256 + threadIdx.x;   // 0..16383, 4 elems each
  const float* srcs[4] = {Wq, Wk, Wv, Wo};
#pragma unroll
  for (int m = 0; m < 4; ++m) {
    floatx4 a = ((const floatx4*)srcs[m])[i];
    short4v s = { f2bf(a[0]), f2bf(a[1]), f2bf(a[2]), f2bf(a[3]) };
    ((short4v*)(wb + m * 16384))[i] = s;
  }
}

// ---------------------------------------------------------------- K1: k,v proj + ctx/Z
__global__ __launch_bounds__(256, 2) void k_kv_ctx(
    const float* __restrict__ x, const short* __restrict__ Wkb,
    const short* __restrict__ Wvb, float* __restrict__ ctx_u,
    float* __restrict__ Zsum) {
  __shared__ float natx[C_ * NB];        // [128][64] f32, 32 KB
  __shared__ short ekbuf[C_ * STV];      // 18 KB
  __shared__ short vbuf [C_ * STV];      // 18 KB
  const int tid = threadIdx.x;
  const int w = tid >> 6, L = tid & 63, l15 = tid & 15, q4 = (tid & 63) >> 4;
  const int b = blockIdx.x / NSTRIP;
  const int strip = blockIdx.x % NSTRIP;
  const float* xb = x + (size_t)b * C_ * N_;

  // register-resident A-frags for both weights
  short8 ak[2][4], av[2][4];
#pragma unroll
  for (int mt = 0; mt < 2; ++mt)
#pragma unroll
    for (int ks = 0; ks < 4; ++ks) {
      ak[mt][ks] = *(const short8*)&Wkb[(w * 32 + mt * 16 + l15) * C_ + ks * 32 + q4 * 8];
      av[mt][ks] = *(const short8*)&Wvb[(w * 32 + mt * 16 + l15) * C_ + ks * 32 + q4 * 8];
    }

  const floatx4 z4 = {0.f, 0.f, 0.f, 0.f};
  floatx4 ca[2][2] = {{z4, z4}, {z4, z4}};   // ctx accumulator across tiles
  float zreg[2][4] = {{0.f,0.f,0.f,0.f},{0.f,0.f,0.f,0.f}};

  // stage tile 0
#pragma unroll
  for (int i = 0; i < 8; ++i) {
    const int c = w * 32 + i * 4 + (L >> 4);
    gload_lds16(xb + (size_t)c * N_ + (size_t)(strip * TPB) * NB + (L & 15) * 4,
                (char*)natx + ((w * 32 + i * 4) * NB + L * 4) * 4);
  }

  for (int t = 0; t < TPB; ++t) {
    __syncthreads();   // b1: stage(t) visible

    floatx4 acck[2][4], accv[2][4];
#pragma unroll
    for (int mt = 0; mt < 2; ++mt)
#pragma unroll
      for (int nt = 0; nt < 4; ++nt) { acck[mt][nt] = z4; accv[mt][nt] = z4; }

    // k and v GEMMs; B-frags built from natural-layout LDS (transpose folded)
#pragma unroll
    for (int ks = 0; ks < 4; ++ks) {
      short8 Bf[4];
#pragma unroll
      for (int nt = 0; nt < 4; ++nt) {
        short8 s;
#pragma unroll
        for (int j = 0; j < 8; ++j)
          s[j] = f2bf(natx[(ks * 32 + q4 * 8 + j) * NB + nt * 16 + l15]);
        Bf[nt] = s;
      }
#pragma unroll
      for (int mt = 0; mt < 2; ++mt)
#pragma unroll
        for (int nt = 0; nt < 4; ++nt) {
          acck[mt][nt] = __builtin_amdgcn_mfma_f32_16x16x32_bf16(ak[mt][ks], Bf[nt], acck[mt][nt], 0, 0, 0);
          accv[mt][nt] = __builtin_amdgcn_mfma_f32_16x16x32_bf16(av[mt][ks], Bf[nt], accv[mt][nt], 0, 0, 0);
        }
    }
    __syncthreads();   // b2: natx reads done -> restage allowed

    // prefetch stage(t+1) — flies during the wave-local phase below
    if (t + 1 < TPB) {
#pragma unroll
      for (int i = 0; i < 8; ++i) {
        const int c = w * 32 + i * 4 + (L >> 4);
        gload_lds16(xb + (size_t)c * N_ + (size_t)(strip * TPB + t + 1) * NB + (L & 15) * 4,
                    (char*)natx + ((w * 32 + i * 4) * NB + L * 4) * 4);
      }
    }

    // exp(k) + Z partial accumulation in registers
#pragma unroll
    for (int mt = 0; mt < 2; ++mt)
#pragma unroll
      for (int nt = 0; nt < 4; ++nt)
#pragma unroll
        for (int r = 0; r < 4; ++r)
          acck[mt][nt][r] = __expf(acck[mt][nt][r]);
#pragma unroll
    for (int mt = 0; mt < 2; ++mt)
#pragma unroll
      for (int r = 0; r < 4; ++r)
        zreg[mt][r] += acck[mt][0][r] + acck[mt][1][r] + acck[mt][2][r] + acck[mt][3][r];

    // pack ek, v into wave-local LDS rows (in-wave DS ordering, no barrier)
#pragma unroll
    for (int mt = 0; mt < 2; ++mt)
#pragma unroll
      for (int nt = 0; nt < 4; ++nt)
#pragma unroll
        for (int r = 0; r < 4; ++r) {
          ekbuf[(w * 32 + mt * 16 + q4 * 4 + r) * STV + nt * 16 + l15] = f2bf(acck[mt][nt][r]);
          vbuf [(w * 32 + mt * 16 + q4 * 4 + r) * STV + nt * 16 + l15] = f2bf(accv[mt][nt][r]);
        }

    // ctx partial via MFMA (wave-local rows), accumulates across tiles
#pragma unroll
    for (int ks = 0; ks < 2; ++ks) {
      short8 ae[2], be[2];
#pragma unroll
      for (int mt = 0; mt < 2; ++mt)
        ae[mt] = *(const short8*)&ekbuf[(w * 32 + mt * 16 + l15) * STV + ks * 32 + q4 * 8];
#pragma unroll
      for (int nt = 0; nt < 2; ++nt)
        be[nt] = *(const short8*)&vbuf[(w * 32 + nt * 16 + l15) * STV + ks * 32 + q4 * 8];
#pragma unroll
      for (int mt = 0; mt < 2; ++mt)
#pragma unroll
        for (int nt = 0; nt < 2; ++nt)
          ca[mt][nt] = __builtin_amdgcn_mfma_f32_16x16x32_bf16(ae[mt], be[nt], ca[mt][nt], 0, 0, 0);
    }
  }

  // Z: reduce over l15, one atomic per row
#pragma unroll
  for (int mt = 0; mt < 2; ++mt)
#pragma unroll
    for (int r = 0; r < 4; ++r) {
      float s = zreg[mt][r];
      s += __shfl_xor(s, 1); s += __shfl_xor(s, 2);
      s += __shfl_xor(s, 4); s += __shfl_xor(s, 8);
      if (l15 == 0) atomicAdd(&Zsum[b * HID + w * 32 + mt * 16 + q4 * 4 + r], s);
    }

  // ctx atomics (once per block)
  float* cb = &ctx_u[((size_t)b * H_ + w) * (D_ * D_)];
#pragma unroll
  for (int mt = 0; mt < 2; ++mt)
#pragma unroll
    for (int nt = 0; nt < 2; ++nt)
#pragma unroll
      for (int r = 0; r < 4; ++r)
        atomicAdd(&cb[(mt * 16 + q4 * 4 + r) * D_ + nt * 16 + l15], ca[mt][nt][r]);
}

// ---------------------------------------------------------------- K2: q proj + attn + Wo + stats
__global__ __launch_bounds__(256, 2) void k_q_attn_o(
    const float* __restrict__ x, const short* __restrict__ Wqb,
    const short* __restrict__ Wob, const float* __restrict__ bo,
    const float* __restrict__ ctx_u, const float* __restrict__ Zsum,
    float* __restrict__ outp, float* __restrict__ stats) {
  __shared__ float natx[C_ * NB];     // 32 KB
  __shared__ short qat[NB * STA];     // eq^T then attn^T, 17 KB
  __shared__ short ctxT[HID * SCT];   // 10 KB
  const int tid = threadIdx.x;
  const int w = tid >> 6, L = tid & 63, l15 = tid & 15, q4 = (tid & 63) >> 4;
  const int b = blockIdx.x / NSTRIP;
  const int strip = blockIdx.x % NSTRIP;
  const float* xb = x + (size_t)b * C_ * N_;

  // stage tile 0 (async), then fill ctxT while loads fly
#pragma unroll
  for (int i = 0; i < 8; ++i) {
    const int c = w * 32 + i * 4 + (L >> 4);
    gload_lds16(xb + (size_t)c * N_ + (size_t)(strip * TPB) * NB + (L & 15) * 4,
                (char*)natx + ((w * 32 + i * 4) * NB + L * 4) * 4);
  }
#pragma unroll
  for (int i = 0; i < 16; ++i) {
    const int idx = tid + i * 256;               // h*1024 + d*32 + e
    float v = ctx_u[(size_t)b * (H_ * D_ * D_) + idx] *
              __builtin_amdgcn_rcpf(Zsum[b * HID + (idx >> 5)]);
    ctxT[((idx >> 10) * 32 + (idx & 31)) * SCT + ((idx >> 5) & 31)] = f2bf(v);
  }

  // register-resident A-frags for Wq and Wo
  short8 aq[2][4], ao[2][4];
#pragma unroll
  for (int mt = 0; mt < 2; ++mt)
#pragma unroll
    for (int ks = 0; ks < 4; ++ks) {
      aq[mt][ks] = *(const short8*)&Wqb[(w * 32 + mt * 16 + l15) * C_ + ks * 32 + q4 * 8];
      ao[mt][ks] = *(const short8*)&Wob[(w * 32 + mt * 16 + l15) * HID + ks * 32 + q4 * 8];
    }

  const floatx4 z4 = {0.f, 0.f, 0.f, 0.f};
  float s1 = 0.f, s2 = 0.f;

  for (int t = 0; t < TPB; ++t) {
    const int n0 = (strip * TPB + t) * NB;
    __syncthreads();   // b1: stage(t) + (t==0) ctxT visible

    // q = Wq @ x
    floatx4 acc[2][4];
#pragma unroll
    for (int mt = 0; mt < 2; ++mt)
#pragma unroll
      for (int nt = 0; nt < 4; ++nt) acc[mt][nt] = z4;
#pragma unroll
    for (int ks = 0; ks < 4; ++ks) {
      short8 Bf[4];
#pragma unroll
      for (int nt = 0; nt < 4; ++nt) {
        short8 s;
#pragma unroll
        for (int j = 0; j < 8; ++j)
          s[j] = f2bf(natx[(ks * 32 + q4 * 8 + j) * NB + nt * 16 + l15]);
        Bf[nt] = s;
      }
#pragma unroll
      for (int mt = 0; mt < 2; ++mt)
#pragma unroll
        for (int nt = 0; nt < 4; ++nt)
          acc[mt][nt] = __builtin_amdgcn_mfma_f32_16x16x32_bf16(aq[mt][ks], Bf[nt], acc[mt][nt], 0, 0, 0);
    }
    __syncthreads();   // b2: natx reads done -> restage allowed

    // prefetch stage(t+1)
    if (t + 1 < TPB) {
#pragma unroll
      for (int i = 0; i < 8; ++i) {
        const int c = w * 32 + i * 4 + (L >> 4);
        gload_lds16(xb + (size_t)c * N_ + (size_t)(n0 + NB) + (L & 15) * 4,
                    (char*)natx + ((w * 32 + i * 4) * NB + L * 4) * 4);
      }
    }

    // exp(q); per-column softmax denom via shuffle
#pragma unroll
    for (int mt = 0; mt < 2; ++mt)
#pragma unroll
      for (int nt = 0; nt < 4; ++nt)
#pragma unroll
        for (int r = 0; r < 4; ++r)
          acc[mt][nt][r] = __expf(acc[mt][nt][r]);
    float inv[4];
#pragma unroll
    for (int nt = 0; nt < 4; ++nt) {
      float s = 0.f;
#pragma unroll
      for (int mt = 0; mt < 2; ++mt)
#pragma unroll
        for (int r = 0; r < 4; ++r) s += acc[mt][nt][r];
      s += __shfl_xor(s, 16); s += __shfl_xor(s, 32);
      inv[nt] = SCALE * __builtin_amdgcn_rcpf(s);
    }

    // scaled eq^T into qat (wave-local columns)
#pragma unroll
    for (int mt = 0; mt < 2; ++mt)
#pragma unroll
      for (int nt = 0; nt < 4; ++nt) {
        short4v pk = { f2bf(acc[mt][nt][0] * inv[nt]), f2bf(acc[mt][nt][1] * inv[nt]),
                       f2bf(acc[mt][nt][2] * inv[nt]), f2bf(acc[mt][nt][3] * inv[nt]) };
        *(short4v*)&qat[(nt * 16 + l15) * STA + w * 32 + mt * 16 + q4 * 4] = pk;
      }

    // attn: out[e][n] = sum_d ctxT[e][d] * eq[d][n]   (wave-local)
    {
      floatx4 aacc[2][4];
#pragma unroll
      for (int mt = 0; mt < 2; ++mt)
#pragma unroll
        for (int nt = 0; nt < 4; ++nt) aacc[mt][nt] = z4;
      short8 ae[2];
#pragma unroll
      for (int mt = 0; mt < 2; ++mt)
        ae[mt] = *(const short8*)&ctxT[(w * 32 + mt * 16 + l15) * SCT + q4 * 8];
#pragma unroll
      for (int nt = 0; nt < 4; ++nt) {
        short8 bq = *(const short8*)&qat[(nt * 16 + l15) * STA + w * 32 + q4 * 8];
#pragma unroll
        for (int mt = 0; mt < 2; ++mt)
          aacc[mt][nt] = __builtin_amdgcn_mfma_f32_16x16x32_bf16(ae[mt], bq, aacc[mt][nt], 0, 0, 0);
      }
      // attn^T over eq^T (same wave-local columns)
#pragma unroll
      for (int nt = 0; nt < 4; ++nt)
#pragma unroll
        for (int mt = 0; mt < 2; ++mt) {
          short4v pk = { f2bf(aacc[mt][nt][0]), f2bf(aacc[mt][nt][1]),
                         f2bf(aacc[mt][nt][2]), f2bf(aacc[mt][nt][3]) };
          *(short4v*)&qat[(nt * 16 + l15) * STA + w * 32 + mt * 16 + q4 * 4] = pk;
        }
    }
    __syncthreads();   // b3: attn^T visible to all waves

    // out_pre = Wo @ attn + bo
    floatx4 oacc[2][4];
#pragma unroll
    for (int mt = 0; mt < 2; ++mt)
#pragma unroll
      for (int nt = 0; nt < 4; ++nt) oacc[mt][nt] = z4;
#pragma unroll
    for (int ks = 0; ks < 4; ++ks) {
      short8 bf8[4];
#pragma unroll
      for (int nt = 0; nt < 4; ++nt)
        bf8[nt] = *(const short8*)&qat[(nt * 16 + l15) * STA + ks * 32 + q4 * 8];
#pragma unroll
      for (int mt = 0; mt < 2; ++mt)
#pragma unroll
        for (int nt = 0; nt < 4; ++nt)
          oacc[mt][nt] = __builtin_amdgcn_mfma_f32_16x16x32_bf16(ao[mt][ks], bf8[nt], oacc[mt][nt], 0, 0, 0);
    }

    // epilogue: +bo, store, accumulate stats in registers
#pragma unroll
    for (int mt = 0; mt < 2; ++mt) {
      const int rowbase = w * 32 + mt * 16 + q4 * 4;
      const floatx4 bo4 = *(const floatx4*)&bo[rowbase];
#pragma unroll
      for (int nt = 0; nt < 4; ++nt) {
        const int n = n0 + nt * 16 + l15;
#pragma unroll
        for (int r = 0; r < 4; ++r) {
          float vv = oacc[mt][nt][r] + bo4[r];
          outp[(size_t)b * (C_ * N_) + (size_t)(rowbase + r) * N_ + n] = vv;
          s1 += vv; s2 += vv * vv;
        }
      }
    }
  }

  // stats: wave reduce + one atomic pair per wave
#pragma unroll
  for (int m = 1; m < 64; m <<= 1) {
    s1 += __shfl_xor(s1, m);
    s2 += __shfl_xor(s2, m);
  }
  if ((tid & 63) == 0) {
    atomicAdd(&stats[b * 2 + 0], s1);
    atomicAdd(&stats[b * 2 + 1], s2);
  }
}

// ---------------------------------------------------------------- K3: GroupNorm
__global__ __launch_bounds__(256) void k_gnorm(
    float* __restrict__ outp, const float* __restrict__ stats,
    const float* __restrict__ gnw, const float* __restrict__ gnb) {
  const int b = blockIdx.x >> 6;
  const int blk = blockIdx.x & 63;
  const float M = (float)(C_ * N_);
  const float mu = stats[b * 2 + 0] / M;
  const float var = stats[b * 2 + 1] / M - mu * mu;
  const float rs = rsqrtf(var + EPS);
  floatx4* p = (floatx4*)(outp + (size_t)b * (C_ * N_) + (size_t)blk * 8192);
  const int tid = threadIdx.x;
#pragma unroll
  for (int i = 0; i < 8; ++i) {
    const int idx = tid + i * 256;
    const int fl = blk * 8192 + idx * 4;
    const int c = fl >> 12;
    const float wgt = gnw[c] * rs;
    const float bia = gnb[c] - mu * wgt;
    floatx4 v = p[idx];
    v[0] = v[0] * wgt + bia;
    v[1] = v[1] * wgt + bia;
    v[2] = v[2] * wgt + bia;
    v[3] = v[3] * wgt + bia;
    p[idx] = v;
  }
}

// ---------------------------------------------------------------- launch
extern "C" void kernel_launch(void* const* d_in, const int* in_sizes, int n_in,
                              void* d_out, int out_size, void* d_ws, size_t ws_size,
                              hipStream_t stream) {
  (void)in_sizes; (void)n_in; (void)out_size; (void)ws_size;
  const float* x   = (const float*)d_in[0];
  const float* Wq  = (const float*)d_in[1];
  const float* Wk  = (const float*)d_in[2];
  const float* Wv  = (const float*)d_in[3];
  const float* Wo  = (const float*)d_in[4];
  const float* bo  = (const float*)d_in[5];
  const float* gnw = (const float*)d_in[6];
  const float* gnb = (const float*)d_in[7];
  float* outp  = (float*)d_out;
  float* ctx_u = (float*)d_ws;                       // 131072 f
  float* Zsum  = ctx_u + B_ * H_ * D_ * D_;          // 4096 f
  float* stats = Zsum + B_ * HID;                    // 64 f
  short* wb    = (short*)(stats + B_ * 2);           // 4 x 16384 bf16
  const size_t zbytes = (size_t)(B_ * H_ * D_ * D_ + B_ * HID + B_ * 2) * sizeof(float);
  hipMemsetAsync(d_ws, 0, zbytes, stream);
  hipLaunchKernelGGL(k_wcast,    dim3(64),           dim3(256), 0, stream, Wq, Wk, Wv, Wo, wb);
  hipLaunchKernelGGL(k_kv_ctx,   dim3(B_ * NSTRIP),  dim3(256), 0, stream, x, wb + 16384, wb + 32768, ctx_u, Zsum);
  hipLaunchKernelGGL(k_q_attn_o, dim3(B_ * NSTRIP),  dim3(256), 0, stream, x, wb, wb + 49152, bo, ctx_u, Zsum, outp, stats);
  hipLaunchKernelGGL(k_gnorm,    dim3(B_ * 64),      dim3(256), 0, stream, outp, stats, gnw, gnb);
}